// Round 4
// baseline (614.267 us; speedup 1.0000x reference)
//
#include <hip/hip_runtime.h>
#include <hip/hip_bf16.h>

// ---------------------------------------------------------------------------
// EncoderBlock: B=4 T=2048 E=1024 H=16 hd=64 F=4096. fp32 in/out, bf16 MFMA.
// R8: GEMMs rewritten as 256x256-tile 8-wave double-buffered pipeline
// (per-wave 128x64 -> 0.375 ds_read/MFMA, MFMA-bound; raw s_barrier +
// vmcnt(0), 1 barrier/K-step, stage overlapped with compute). QKV fused into
// one N=3072 GEMM (Wq/Wk/Wv bf16 copies are contiguous). Flash reverted to
// the measured-best R6 version (144us).
// ---------------------------------------------------------------------------

typedef __attribute__((ext_vector_type(8))) short  short8;   // 8 bf16 = 16B
typedef __attribute__((ext_vector_type(4))) float  f32x4;
typedef __attribute__((ext_vector_type(4))) int    i32x4;
typedef __attribute__((ext_vector_type(4))) unsigned short u16x4;     // 8B

__device__ inline float b2f(unsigned short u) {
    unsigned int x = ((unsigned int)u) << 16;
    return __builtin_bit_cast(float, x);
}
__device__ inline unsigned short f2b(float f) {
    return __builtin_bit_cast(unsigned short, __float2bfloat16(f));
}

// async global->LDS, 16B/lane (m97 fast path)
__device__ inline void llds16(const unsigned short* g, unsigned short* l) {
    __builtin_amdgcn_global_load_lds(
        (const __attribute__((address_space(1))) unsigned int*)g,
        (__attribute__((address_space(3))) unsigned int*)l, 16, 0, 0);
}

// swizzled element offset of 16B-block (row, col8) in a 64-col bf16 tile
__device__ inline int swz(int row, int col8) {
    return (row << 6) + (((col8 ^ (row >> 1)) & 7) << 3);
}

// ---------------------------------------------------------------------------
__global__ __launch_bounds__(256)
void cast_f32_bf16(const float* __restrict__ in, unsigned short* __restrict__ out,
                   int n4)
{
    int i = blockIdx.x * 256 + threadIdx.x;
    if (i >= n4) return;
    f32x4 v = *(const f32x4*)(in + (size_t)i * 4);
    u16x4 o;
    for (int j = 0; j < 4; ++j) o[j] = f2b(v[j]);
    *(u16x4*)(out + (size_t)i * 4) = o;
}

__global__ __launch_bounds__(256)
void mask_bf16(const int* __restrict__ m, unsigned short* __restrict__ mb, int n)
{
    int i = blockIdx.x * 256 + threadIdx.x;
    if (i < n) mb[i] = m[i] ? (unsigned short)0x3F80 : (unsigned short)0;  // bf16 1.0/0.0
}

// ---------------------------------------------------------------------------
// gemm256: C(M,N) = A(M,K) @ W(N,K)^T [+bias][+relu], bf16, fp32 accum.
// 256x256 tile, BK=64, 512 thr = 8 waves (2M x 4N), per-wave 128x64
// (af[8] x bf[4] -> 32 MFMA per ks, 12 ds_read_b128: MFMA-bound).
// Double-buffered LDS (128KB), ONE raw s_barrier + vmcnt(0) per K-step;
// next tile's global_load_lds issued after the barrier, lands under the
// ~2400cyc of MFMA (HBM latency fully hidden; no __syncthreads drain).
// QKV=1: N=3072 fused; per-block segment bn>>2: 0->q, 1->kk, 2->vt
// (transposed [b][h][d][t], masked rows zeroed). Out stride E=1024.
// ---------------------------------------------------------------------------
template <int BIAS, int RELU, int QKV>
__global__ __launch_bounds__(512, 2)
void gemm256(const unsigned short* __restrict__ A,
             const unsigned short* __restrict__ W,
             const float* __restrict__ bias,
             const int* __restrict__ mask,
             unsigned short* __restrict__ C0,
             unsigned short* __restrict__ C1,
             unsigned short* __restrict__ C2,
             int M, int N, int K)
{
    __shared__ __attribute__((aligned(16))) unsigned short a_s[2][256 * 64];
    __shared__ __attribute__((aligned(16))) unsigned short b_s[2][256 * 64];

    const int tid  = threadIdx.x;
    const int lane = tid & 63;
    const int w    = tid >> 6;
    const int ln   = lane & 15;
    const int quad = lane >> 4;
    const int wm   = w >> 2, wn = w & 3;      // 2M x 4N waves
    const int bm   = blockIdx.y, bn = blockIdx.x;

    f32x4 acc[8][4] = {};

    auto stage = [&](int buf, int kt) {
#pragma unroll
        for (int i = 0; i < 4; ++i) {
            int e   = i * 512 + tid;          // 16B block 0..2047 of 256x64 tile
            int row = e >> 3;
            int c8  = (e & 7) ^ ((e >> 4) & 7);   // source perm = swizzle
            llds16(A + (size_t)(bm * 256 + row) * K + kt * 64 + c8 * 8,
                   &a_s[buf][e * 8]);
            llds16(W + (size_t)(bn * 256 + row) * K + kt * 64 + c8 * 8,
                   &b_s[buf][e * 8]);
        }
    };

    const int nkt = K >> 6;
    stage(0, 0);                              // prologue
    for (int kt = 0; kt < nkt; ++kt) {
        const int cur = kt & 1;
        asm volatile("s_waitcnt vmcnt(0)" ::: "memory");   // own S(kt) done
        __builtin_amdgcn_s_barrier();         // all S(kt) in LDS; prev compute done
        if (kt + 1 < nkt) stage(cur ^ 1, kt + 1);          // overlaps with MFMA
#pragma unroll
        for (int ks = 0; ks < 2; ++ks) {
            short8 af[8], bf_[4];
#pragma unroll
            for (int mt = 0; mt < 8; ++mt)
                af[mt] = *(const short8*)&a_s[cur][swz(wm * 128 + mt * 16 + ln, ks * 4 + quad)];
#pragma unroll
            for (int nt = 0; nt < 4; ++nt)
                bf_[nt] = *(const short8*)&b_s[cur][swz(wn * 64 + nt * 16 + ln, ks * 4 + quad)];
            __builtin_amdgcn_s_setprio(1);
#pragma unroll
            for (int mt = 0; mt < 8; ++mt)
#pragma unroll
                for (int nt = 0; nt < 4; ++nt)
                    acc[mt][nt] = __builtin_amdgcn_mfma_f32_16x16x32_bf16(
                        af[mt], bf_[nt], acc[mt][nt], 0, 0, 0);
            __builtin_amdgcn_s_setprio(0);
        }
    }

    // C/D layout: col=lane&15, row=quad*4+reg
    const int crow0 = bm * 256 + wm * 128;
    const int ccol0 = bn * 256 + wn * 64;
    if (QKV) {
        const int seg  = bn >> 2;             // 0=q 1=kk 2=vt (block within one seg)
        const int lc0  = ccol0 & 1023;
        if (seg < 2) {
            unsigned short* C = seg == 0 ? C0 : C1;
#pragma unroll
            for (int nt = 0; nt < 4; ++nt) {
                int col = lc0 + nt * 16 + ln;
#pragma unroll
                for (int mt = 0; mt < 8; ++mt) {
                    int row0 = crow0 + mt * 16 + quad * 4;
#pragma unroll
                    for (int r = 0; r < 4; ++r)
                        C[(size_t)(row0 + r) * 1024 + col] = f2b(acc[mt][nt][r]);
                }
            }
        } else {
            const int T2 = 2048, H2 = 16;
#pragma unroll
            for (int mt = 0; mt < 8; ++mt) {
                int row0 = crow0 + mt * 16 + quad * 4;
                int bb = row0 >> 11, t0 = row0 & 2047;
                i32x4 mi = *(const i32x4*)&mask[bb * 2048 + t0];
#pragma unroll
                for (int nt = 0; nt < 4; ++nt) {
                    int col = lc0 + nt * 16 + ln;
                    int hh2 = col >> 6, d = col & 63;
                    u16x4 o;
#pragma unroll
                    for (int r = 0; r < 4; ++r)
                        o[r] = mi[r] ? f2b(acc[mt][nt][r]) : (unsigned short)0;
                    *(u16x4*)(C2 + ((size_t)((bb * H2 + hh2) * 64 + d)) * T2 + t0) = o;
                }
            }
        }
    } else {
#pragma unroll
        for (int nt = 0; nt < 4; ++nt) {
            int col = ccol0 + nt * 16 + ln;
            float bv = 0.f;
            if (BIAS) bv = bias[col];
#pragma unroll
            for (int mt = 0; mt < 8; ++mt) {
                int row0 = crow0 + mt * 16 + quad * 4;
#pragma unroll
                for (int r = 0; r < 4; ++r) {
                    float v = acc[mt][nt][r] + bv;
                    if (RELU) v = v > 0.f ? v : 0.f;
                    C0[(size_t)(row0 + r) * N + col] = f2b(v);
                }
            }
        }
    }
}

// ---------------------------------------------------------------------------
// Flash attention (R6, measured 144us). Block = 8 waves = one (b,h,128 q);
// wave = 16 q. Maskless k-loop: V rows pre-zeroed for masked keys; l = P@m01
// via MFMA. Fixed-max softmax p = exp2(s*0.125*log2e). K/V double-buffered,
// 1 barrier/tile, staged once per 128 q-rows. Q staged into p_s (wave-private
// aliasing). LDS 48KB -> 3 blk/CU, 24 wv/CU. Grid 1024, XCD-swizzled.
// ---------------------------------------------------------------------------
__global__ __launch_bounds__(512, 2)
void flash_attn3(const unsigned short* __restrict__ Q,
                 const unsigned short* __restrict__ K,
                 const unsigned short* __restrict__ Vt,
                 const unsigned short* __restrict__ mb,
                 const int* __restrict__ mask,
                 unsigned short* __restrict__ O,
                 int T, int H, int E)
{
    __shared__ __attribute__((aligned(16))) unsigned short k_s[2][64 * 64];
    __shared__ __attribute__((aligned(16))) unsigned short v_s[2][64 * 64];
    __shared__ __attribute__((aligned(16))) unsigned short p_s[128 * 64];

    // bijective XCD swizzle: 1024 blocks % 8 == 0; XCD x owns 8 (b,h) panels
    const int ord = blockIdx.x;
    const int wg  = (ord & 7) * 128 + (ord >> 3);
    const int qt  = wg & 15;          // T/128 = 16
    const int h   = (wg >> 4) & 15;   // H  = 16
    const int b   = wg >> 8;          // B  = 4

    const int tid  = threadIdx.x;
    const int w    = tid >> 6;
    const int lane = tid & 63;
    const int ln   = lane & 15;
    const int quad = lane >> 4;
    const int q0   = qt * 128;
    const unsigned short* vt_b = Vt + (size_t)(b * H + h) * 64 * T;

    // stage Q (128 rows, into p_s region) + K/V tile 0
    {
        int e = tid;                        // 512 x 16B = one 64x64 tile
        int row = e >> 3;
        int c8  = (e & 7) ^ ((e >> 4) & 7);
        llds16(K + (size_t)(b * T + row) * E + h * 64 + c8 * 8, &k_s[0][e * 8]);
        llds16(vt_b + (size_t)row * T + c8 * 8, &v_s[0][e * 8]);
    }
    for (int i = 0; i < 2; ++i) {
        int e = i * 512 + tid;              // 1024 x 16B = 128x64 Q tile
        int row = e >> 3;
        int c8  = (e & 7) ^ ((e >> 4) & 7);
        llds16(Q + (size_t)(b * T + q0 + row) * E + h * 64 + c8 * 8, &p_s[e * 8]);
    }
    __syncthreads();
    short8 aq[2];   // wave w reads only rows w*16..w*16+15 => its own p_s slice
    aq[0] = *(const short8*)&p_s[w * 1024 + swz(ln, quad)];
    aq[1] = *(const short8*)&p_s[w * 1024 + swz(ln, 4 + quad)];

    f32x4 Oa[4] = {};
    f32x4 lacc = {};
    const float SCL = 0.125f * 1.44269504f;

    const int nkb = T >> 6;
    for (int kb = 0; kb < nkb; ++kb) {
        const int cur = kb & 1;
        if (kb + 1 < nkb) {     // async prefetch next K/V tile; drains at barrier
            int e = tid;
            int row = e >> 3;
            int c8  = (e & 7) ^ ((e >> 4) & 7);
            llds16(K + (size_t)(b * T + (kb + 1) * 64 + row) * E + h * 64 + c8 * 8,
                   &k_s[cur ^ 1][e * 8]);
            llds16(vt_b + (size_t)row * T + (kb + 1) * 64 + c8 * 8,
                   &v_s[cur ^ 1][e * 8]);
        }
        // m01 B-frags (16B/lane, L2-hot)
        short8 mf0 = *(const short8*)&mb[b * T + kb * 64 + quad * 8];
        short8 mf1 = *(const short8*)&mb[b * T + kb * 64 + 32 + quad * 8];

        // S = Q K^T : 8 MFMAs
        f32x4 S[4] = {};
        for (int ks = 0; ks < 2; ++ks)
            for (int nt = 0; nt < 4; ++nt) {
                short8 bf_ = *(const short8*)&k_s[cur][swz(nt * 16 + ln, ks * 4 + quad)];
                S[nt] = __builtin_amdgcn_mfma_f32_16x16x32_bf16(aq[ks], bf_, S[nt], 0, 0, 0);
            }
        // P = exp2(S*scl), write to wave-private p_s (swizzled, conflict-free)
        for (int nt = 0; nt < 4; ++nt)
            for (int r = 0; r < 4; ++r) {
                float p = exp2f(S[nt][r] * SCL);
                p_s[w * 1024 + swz(quad * 4 + r, 2 * nt + (ln >> 3)) + (ln & 7)] = f2b(p);
            }
        short8 ap0 = *(const short8*)&p_s[w * 1024 + swz(ln, quad)];
        short8 ap1 = *(const short8*)&p_s[w * 1024 + swz(ln, 4 + quad)];
        // l += P @ m01  (masked row-sum, lands exactly in C-layout rows)
        lacc = __builtin_amdgcn_mfma_f32_16x16x32_bf16(ap0, mf0, lacc, 0, 0, 0);
        lacc = __builtin_amdgcn_mfma_f32_16x16x32_bf16(ap1, mf1, lacc, 0, 0, 0);
        // O += P @ V  (masked V rows are zero)
        for (int nt = 0; nt < 4; ++nt) {
            short8 bv0 = *(const short8*)&v_s[cur][swz(nt * 16 + ln, quad)];
            Oa[nt] = __builtin_amdgcn_mfma_f32_16x16x32_bf16(ap0, bv0, Oa[nt], 0, 0, 0);
            short8 bv1 = *(const short8*)&v_s[cur][swz(nt * 16 + ln, 4 + quad)];
            Oa[nt] = __builtin_amdgcn_mfma_f32_16x16x32_bf16(ap1, bv1, Oa[nt], 0, 0, 0);
        }
        __syncthreads();   // k_s/v_s swap + prefetch drain
    }

    for (int r = 0; r < 4; ++r) {
        int qrow = q0 + w * 16 + quad * 4 + r;
        float inv = mask[b * T + qrow] ? 1.f / lacc[r] : 0.f;
        for (int nt = 0; nt < 4; ++nt)
            O[(size_t)(b * T + qrow) * E + h * 64 + nt * 16 + ln] = f2b(Oa[nt][r] * inv);
    }
}

// ---------------------------------------------------------------------------
// LayerNorm(a + r): mean over E, std ddof=1, y=(v-mean)/(sd+eps)*g+b.
// ---------------------------------------------------------------------------
template <int R_F32, int O_F32>
__global__ __launch_bounds__(256, 4)
void ln_residual(const unsigned short* __restrict__ A,
                 const void* __restrict__ R,
                 const float* __restrict__ G,
                 const float* __restrict__ Bt,
                 void* __restrict__ Y, int E)
{
    const int row = blockIdx.x;
    const int tid = threadIdx.x;
    size_t base = (size_t)row * E + tid * 4;
    u16x4 a4 = *(const u16x4*)(A + base);
    float rv[4];
    if (R_F32) {
        f32x4 r4 = *(const f32x4*)((const float*)R + base);
        for (int j = 0; j < 4; ++j) rv[j] = r4[j];
    } else {
        u16x4 r4 = *(const u16x4*)((const unsigned short*)R + base);
        for (int j = 0; j < 4; ++j) rv[j] = b2f(r4[j]);
    }
    float v[4]; float s = 0.f, sq = 0.f;
    for (int j = 0; j < 4; ++j) {
        v[j] = b2f(a4[j]) + rv[j];
        s += v[j]; sq += v[j] * v[j];
    }
    for (int o = 32; o; o >>= 1) {
        s  += __shfl_xor(s, o, 64);
        sq += __shfl_xor(sq, o, 64);
    }
    __shared__ float red[8];
    int w = tid >> 6, lane = tid & 63;
    if (lane == 0) { red[w] = s; red[4 + w] = sq; }
    __syncthreads();
    s  = red[0] + red[1] + red[2] + red[3];
    sq = red[4] + red[5] + red[6] + red[7];
    float mean = s / E;
    float var  = (sq - s * mean) / (E - 1);      // ddof=1
    var = fmaxf(var, 0.f);
    float inv = 1.f / (sqrtf(var) + 1e-5f);
    f32x4 g4 = *(const f32x4*)(G + tid * 4);
    f32x4 b4 = *(const f32x4*)(Bt + tid * 4);
    if (O_F32) {
        f32x4 o4;
        for (int j = 0; j < 4; ++j)
            o4[j] = (v[j] - mean) * inv * g4[j] + b4[j];
        *(f32x4*)((float*)Y + base) = o4;
    } else {
        u16x4 o4;
        for (int j = 0; j < 4; ++j)
            o4[j] = f2b((v[j] - mean) * inv * g4[j] + b4[j]);
        *(u16x4*)((unsigned short*)Y + base) = o4;
    }
}

// ---------------------------------------------------------------------------
extern "C" void kernel_launch(void* const* d_in, const int* in_sizes, int n_in,
                              void* d_out, int out_size, void* d_ws, size_t ws_size,
                              hipStream_t stream)
{
    const int B = 4, T = 2048, E = 1024, F = 4096, H = 16;
    const int M = B * T;

    const float* x  = (const float*)d_in[0];
    const int* mask = (const int*)d_in[1];
    const float* Wq = (const float*)d_in[2];
    const float* Wk = (const float*)d_in[3];
    const float* Wv = (const float*)d_in[4];
    const float* Wo = (const float*)d_in[5];
    const float* w1 = (const float*)d_in[6];
    const float* b1 = (const float*)d_in[7];
    const float* w2 = (const float*)d_in[8];
    const float* b2 = (const float*)d_in[9];
    const float* lg = (const float*)d_in[10];
    const float* lb = (const float*)d_in[11];
    float* out = (float*)d_out;

    char* ws = (char*)d_ws;
    const size_t MB = 1024 * 1024;
    unsigned short* xb  = (unsigned short*)(ws);            // 16 MB
    unsigned short* q   = (unsigned short*)(ws + 16 * MB);  // 16 MB
    unsigned short* kk  = (unsigned short*)(ws + 32 * MB);  // 16 MB
    unsigned short* vt  = (unsigned short*)(ws + 48 * MB);  // 16 MB  [B][H][64][T]
    unsigned short* ctx = (unsigned short*)(ws + 64 * MB);  // 16 MB
    unsigned short* hh  = (unsigned short*)(ws + 80 * MB);  // 16 MB (alive after flash)
    unsigned short* mbf = hh;                                // m01 bf16 [B][T], dead before hh
    unsigned short* ff1 = (unsigned short*)(ws);            // 64 MB overlays xb/q/kk/vt (dead)
    unsigned short* ff2 = ctx;                              // ctx dead by then
    unsigned short* att = q;                                // q dead after attention
    unsigned short* Wqb = (unsigned short*)(ws + 96 * MB);  // Wq/Wk/Wv CONTIGUOUS = [3072][1024]
    unsigned short* Wkb = (unsigned short*)(ws + 98 * MB);
    unsigned short* Wvb = (unsigned short*)(ws + 100 * MB);
    unsigned short* Wob = (unsigned short*)(ws + 102 * MB);
    unsigned short* w1b = (unsigned short*)(ws + 104 * MB); // 8 MB
    unsigned short* w2b = (unsigned short*)(ws + 112 * MB); // 8 MB -> 120 MB total

    dim3 blk(256);
    cast_f32_bf16<<<dim3(M * E / 4 / 256), blk, 0, stream>>>(x,  xb,  M * E / 4);
    cast_f32_bf16<<<dim3(E * E / 4 / 256), blk, 0, stream>>>(Wq, Wqb, E * E / 4);
    cast_f32_bf16<<<dim3(E * E / 4 / 256), blk, 0, stream>>>(Wk, Wkb, E * E / 4);
    cast_f32_bf16<<<dim3(E * E / 4 / 256), blk, 0, stream>>>(Wv, Wvb, E * E / 4);
    cast_f32_bf16<<<dim3(E * E / 4 / 256), blk, 0, stream>>>(Wo, Wob, E * E / 4);
    cast_f32_bf16<<<dim3(F * E / 4 / 256), blk, 0, stream>>>(w1, w1b, F * E / 4);
    cast_f32_bf16<<<dim3(F * E / 4 / 256), blk, 0, stream>>>(w2, w2b, F * E / 4);
    mask_bf16<<<dim3(M / 256), blk, 0, stream>>>(mask, mbf, M);

    dim3 g512(512);
    // fused QKV: N=3072 (Wqb|Wkb|Wvb contiguous); seg 0->q, 1->kk, 2->vt
    gemm256<0, 0, 1><<<dim3(3072 / 256, M / 256), g512, 0, stream>>>(
        xb, Wqb, nullptr, mask, q, kk, vt, M, 3072, E);
    flash_attn3<<<dim3((T / 128) * H * B), g512, 0, stream>>>(q, kk, vt, mbf, mask, ctx, T, H, E);
    gemm256<0, 0, 0><<<dim3(E / 256, M / 256), g512, 0, stream>>>(
        ctx, Wob, nullptr, nullptr, att, nullptr, nullptr, M, E, E);
    ln_residual<1, 0><<<dim3(M), blk, 0, stream>>>(att, x, lg, lb, hh, E);
    gemm256<1, 1, 0><<<dim3(F / 256, M / 256), g512, 0, stream>>>(
        hh, w1b, b1, nullptr, ff1, nullptr, nullptr, M, F, E);
    gemm256<1, 0, 0><<<dim3(E / 256, M / 256), g512, 0, stream>>>(
        ff1, w2b, b2, nullptr, ff2, nullptr, nullptr, M, E, F);
    ln_residual<0, 1><<<dim3(M), blk, 0, stream>>>(ff2, hh, lg, lb, out, E);
}

// Round 5
// 520.781 us; speedup vs baseline: 1.1795x; 1.1795x over previous
//
#include <hip/hip_runtime.h>
#include <hip/hip_bf16.h>

// ---------------------------------------------------------------------------
// EncoderBlock: B=4 T=2048 E=1024 H=16 hd=64 F=4096. fp32 in/out, bf16 MFMA.
// R9: GEMM = 128^2 tile (full grids at all shapes) + double-buffered LDS with
// counted vmcnt(8) -- loads stay in flight across barriers (kills m97's
// pre-barrier drain, the documented ~20% stall). QKV fused into one N=3072
// launch; all 7 casts fused into one kernel. Flash/LN = R6 (measured best).
// ---------------------------------------------------------------------------

typedef __attribute__((ext_vector_type(8))) short  short8;   // 8 bf16 = 16B
typedef __attribute__((ext_vector_type(4))) float  f32x4;
typedef __attribute__((ext_vector_type(4))) int    i32x4;
typedef __attribute__((ext_vector_type(4))) unsigned short u16x4;     // 8B

__device__ inline float b2f(unsigned short u) {
    unsigned int x = ((unsigned int)u) << 16;
    return __builtin_bit_cast(float, x);
}
__device__ inline unsigned short f2b(float f) {
    return __builtin_bit_cast(unsigned short, __float2bfloat16(f));
}

// async global->LDS, 16B/lane (m97 fast path)
__device__ inline void llds16(const unsigned short* g, unsigned short* l) {
    __builtin_amdgcn_global_load_lds(
        (const __attribute__((address_space(1))) unsigned int*)g,
        (__attribute__((address_space(3))) unsigned int*)l, 16, 0, 0);
}

// swizzled element offset of 16B-block (row, col8) in a 64-col bf16 tile
__device__ inline int swz(int row, int col8) {
    return (row << 6) + (((col8 ^ (row >> 1)) & 7) << 3);
}

// ---------------------------------------------------------------------------
// fused f32 -> bf16 cast over 7 arrays (x, Wq, Wk, Wv, Wo, w1, w2).
// Each block = 256 f32x4 units (1024 elems); all segment sizes are multiples.
// ---------------------------------------------------------------------------
struct CastArgs {
    const float* src[7];
    unsigned short* dst[7];
    int blkcum[8];          // cumulative block counts
};

__global__ __launch_bounds__(256)
void cast_all(CastArgs a)
{
    int blk = blockIdx.x;
    int s = 0;
    while (blk >= a.blkcum[s + 1]) ++s;     // uniform per block, <=6 iters
    int i = (blk - a.blkcum[s]) * 256 + threadIdx.x;
    f32x4 v = *(const f32x4*)(a.src[s] + (size_t)i * 4);
    u16x4 o;
    for (int j = 0; j < 4; ++j) o[j] = f2b(v[j]);
    *(u16x4*)(a.dst[s] + (size_t)i * 4) = o;
}

__global__ __launch_bounds__(256)
void mask_bf16(const int* __restrict__ m, unsigned short* __restrict__ mb, int n)
{
    int i = blockIdx.x * 256 + threadIdx.x;
    if (i < n) mb[i] = m[i] ? (unsigned short)0x3F80 : (unsigned short)0;  // bf16 1.0/0.0
}

// ---------------------------------------------------------------------------
// gemm_db: C(M,N) = A(M,K) @ W(N,K)^T [+bias][+relu], bf16, fp32 accum.
// 128x128 tile, BK=64, 256 thr = 4 waves (2x2), per-wave 64x64 (verified
// fragment math). Double-buffered LDS (64KB -> 2 blk/CU); counted-vmcnt
// schedule: stage(kt+2) issued after the read-done barrier, waited with
// vmcnt(8) at the NEXT iteration head -- loads in flight across barriers,
// no drain (m97's ~20% stall removed).
//   invariants: head vmcnt(8)+barrier => tile kt visible to all waves
//               post-MFMA barrier     => all reads of buf[cur] done
// QKV=1: N=3072 fused; seg = bn>>3: 0->q, 1->kk, 2->vt (transposed
// [b][h][d][t], masked rows zeroed). q/kk out-stride 1024.
// ---------------------------------------------------------------------------
template <int BIAS, int RELU, int QKV>
__global__ __launch_bounds__(256, 2)
void gemm_db(const unsigned short* __restrict__ A,
             const unsigned short* __restrict__ W,
             const float* __restrict__ bias,
             const int* __restrict__ mask,
             unsigned short* __restrict__ C0,
             unsigned short* __restrict__ C1,
             unsigned short* __restrict__ C2,
             int M, int N, int K)
{
    __shared__ __attribute__((aligned(16))) unsigned short a_s[2][128 * 64];
    __shared__ __attribute__((aligned(16))) unsigned short b_s[2][128 * 64];

    const int tid  = threadIdx.x;
    const int lane = tid & 63;
    const int w    = tid >> 6;
    const int ln   = lane & 15;
    const int quad = lane >> 4;
    const int wm   = w >> 1, wn = w & 1;
    const int bm   = blockIdx.y, bn = blockIdx.x;

    f32x4 acc[4][4] = {};

    const unsigned short* Abase = A + (size_t)(bm * 128) * K;
    const unsigned short* Wbase = W + (size_t)(bn * 128) * K;

    auto stage = [&](int buf, int kt) {
#pragma unroll
        for (int i = 0; i < 4; ++i) {
            int e   = i * 256 + tid;          // 16B block index 0..1023
            int row = e >> 3;
            int c8  = (e & 7) ^ ((e >> 4) & 7);   // source permutation = swizzle
            llds16(Abase + (size_t)row * K + kt * 64 + c8 * 8, &a_s[buf][e * 8]);
            llds16(Wbase + (size_t)row * K + kt * 64 + c8 * 8, &b_s[buf][e * 8]);
        }
    };

    const int nkt = K >> 6;                   // >= 16 for all our shapes
    stage(0, 0);
    stage(1, 1);
    int cur = 0;
    for (int kt = 0; kt < nkt; ++kt) {
        // wait for tile kt (8 newer loads = tile kt+1 stay in flight)
        if (kt + 1 < nkt) asm volatile("s_waitcnt vmcnt(8)" ::: "memory");
        else              asm volatile("s_waitcnt vmcnt(0)" ::: "memory");
        asm volatile("s_barrier" ::: "memory");      // tile kt visible block-wide
#pragma unroll
        for (int ks = 0; ks < 2; ++ks) {
            short8 af[4], bf_[4];
#pragma unroll
            for (int mt = 0; mt < 4; ++mt)
                af[mt] = *(const short8*)&a_s[cur][swz(wm * 64 + mt * 16 + ln, ks * 4 + quad)];
#pragma unroll
            for (int nt = 0; nt < 4; ++nt)
                bf_[nt] = *(const short8*)&b_s[cur][swz(wn * 64 + nt * 16 + ln, ks * 4 + quad)];
#pragma unroll
            for (int mt = 0; mt < 4; ++mt)
#pragma unroll
                for (int nt = 0; nt < 4; ++nt)
                    acc[mt][nt] = __builtin_amdgcn_mfma_f32_16x16x32_bf16(
                        af[mt], bf_[nt], acc[mt][nt], 0, 0, 0);
        }
        asm volatile("s_barrier" ::: "memory");      // all reads of buf[cur] done
        if (kt + 2 < nkt) stage(cur, kt + 2);        // overwrite old buffer
        cur ^= 1;
    }

    // C/D layout: col=lane&15, row=quad*4+reg
    if (QKV) {
        const int seg = bn >> 3;              // 0=q 1=kk 2=vt
        const int lbn = bn & 7;
        if (seg < 2) {
            unsigned short* C = seg == 0 ? C0 : C1;
#pragma unroll
            for (int nt = 0; nt < 4; ++nt) {
                int col = lbn * 128 + wn * 64 + nt * 16 + ln;
#pragma unroll
                for (int mt = 0; mt < 4; ++mt) {
                    int row0 = bm * 128 + wm * 64 + mt * 16 + quad * 4;
#pragma unroll
                    for (int r = 0; r < 4; ++r)
                        C[(size_t)(row0 + r) * 1024 + col] = f2b(acc[mt][nt][r]);
                }
            }
        } else {
            const int T2 = 2048, H2 = 16;
#pragma unroll
            for (int mt = 0; mt < 4; ++mt) {
                int row0 = bm * 128 + wm * 64 + mt * 16 + quad * 4;
                int bb = row0 >> 11, t0 = row0 & 2047;
                i32x4 mi = *(const i32x4*)&mask[bb * 2048 + t0];
#pragma unroll
                for (int nt = 0; nt < 4; ++nt) {
                    int col = lbn * 128 + wn * 64 + nt * 16 + ln;
                    int hh2 = col >> 6, d = col & 63;
                    u16x4 o;
#pragma unroll
                    for (int r = 0; r < 4; ++r)
                        o[r] = mi[r] ? f2b(acc[mt][nt][r]) : (unsigned short)0;
                    *(u16x4*)(C2 + ((size_t)((bb * H2 + hh2) * 64 + d)) * T2 + t0) = o;
                }
            }
        }
    } else {
#pragma unroll
        for (int nt = 0; nt < 4; ++nt) {
            int col = bn * 128 + wn * 64 + nt * 16 + ln;
            float bv = 0.f;
            if (BIAS) bv = bias[col];
#pragma unroll
            for (int mt = 0; mt < 4; ++mt) {
                int row0 = bm * 128 + wm * 64 + mt * 16 + quad * 4;
#pragma unroll
                for (int r = 0; r < 4; ++r) {
                    float v = acc[mt][nt][r] + bv;
                    if (RELU) v = v > 0.f ? v : 0.f;
                    C0[(size_t)(row0 + r) * N + col] = f2b(v);
                }
            }
        }
    }
}

// ---------------------------------------------------------------------------
// Flash attention (R6, measured 144us). Block = 8 waves = one (b,h,128 q);
// wave = 16 q. Maskless k-loop: V rows pre-zeroed for masked keys; l = P@m01
// via MFMA. Fixed-max softmax p = exp2(s*0.125*log2e). K/V double-buffered,
// 1 barrier/tile, staged once per 128 q-rows. Q staged into p_s (wave-private
// aliasing). LDS 48KB -> 3 blk/CU, 24 wv/CU. Grid 1024, XCD-swizzled.
// ---------------------------------------------------------------------------
__global__ __launch_bounds__(512, 2)
void flash_attn3(const unsigned short* __restrict__ Q,
                 const unsigned short* __restrict__ K,
                 const unsigned short* __restrict__ Vt,
                 const unsigned short* __restrict__ mb,
                 const int* __restrict__ mask,
                 unsigned short* __restrict__ O,
                 int T, int H, int E)
{
    __shared__ __attribute__((aligned(16))) unsigned short k_s[2][64 * 64];
    __shared__ __attribute__((aligned(16))) unsigned short v_s[2][64 * 64];
    __shared__ __attribute__((aligned(16))) unsigned short p_s[128 * 64];

    // bijective XCD swizzle: 1024 blocks % 8 == 0; XCD x owns 8 (b,h) panels
    const int ord = blockIdx.x;
    const int wg  = (ord & 7) * 128 + (ord >> 3);
    const int qt  = wg & 15;          // T/128 = 16
    const int h   = (wg >> 4) & 15;   // H  = 16
    const int b   = wg >> 8;          // B  = 4

    const int tid  = threadIdx.x;
    const int w    = tid >> 6;
    const int lane = tid & 63;
    const int ln   = lane & 15;
    const int quad = lane >> 4;
    const int q0   = qt * 128;
    const unsigned short* vt_b = Vt + (size_t)(b * H + h) * 64 * T;

    // stage Q (128 rows, into p_s region) + K/V tile 0
    {
        int e = tid;                        // 512 x 16B = one 64x64 tile
        int row = e >> 3;
        int c8  = (e & 7) ^ ((e >> 4) & 7);
        llds16(K + (size_t)(b * T + row) * E + h * 64 + c8 * 8, &k_s[0][e * 8]);
        llds16(vt_b + (size_t)row * T + c8 * 8, &v_s[0][e * 8]);
    }
    for (int i = 0; i < 2; ++i) {
        int e = i * 512 + tid;              // 1024 x 16B = 128x64 Q tile
        int row = e >> 3;
        int c8  = (e & 7) ^ ((e >> 4) & 7);
        llds16(Q + (size_t)(b * T + q0 + row) * E + h * 64 + c8 * 8, &p_s[e * 8]);
    }
    __syncthreads();
    short8 aq[2];   // wave w reads only rows w*16..w*16+15 => its own p_s slice
    aq[0] = *(const short8*)&p_s[w * 1024 + swz(ln, quad)];
    aq[1] = *(const short8*)&p_s[w * 1024 + swz(ln, 4 + quad)];

    f32x4 Oa[4] = {};
    f32x4 lacc = {};
    const float SCL = 0.125f * 1.44269504f;

    const int nkb = T >> 6;
    for (int kb = 0; kb < nkb; ++kb) {
        const int cur = kb & 1;
        if (kb + 1 < nkb) {     // async prefetch next K/V tile; drains at barrier
            int e = tid;
            int row = e >> 3;
            int c8  = (e & 7) ^ ((e >> 4) & 7);
            llds16(K + (size_t)(b * T + (kb + 1) * 64 + row) * E + h * 64 + c8 * 8,
                   &k_s[cur ^ 1][e * 8]);
            llds16(vt_b + (size_t)row * T + (kb + 1) * 64 + c8 * 8,
                   &v_s[cur ^ 1][e * 8]);
        }
        // m01 B-frags (16B/lane, L2-hot)
        short8 mf0 = *(const short8*)&mb[b * T + kb * 64 + quad * 8];
        short8 mf1 = *(const short8*)&mb[b * T + kb * 64 + 32 + quad * 8];

        // S = Q K^T : 8 MFMAs
        f32x4 S[4] = {};
        for (int ks = 0; ks < 2; ++ks)
            for (int nt = 0; nt < 4; ++nt) {
                short8 bf_ = *(const short8*)&k_s[cur][swz(nt * 16 + ln, ks * 4 + quad)];
                S[nt] = __builtin_amdgcn_mfma_f32_16x16x32_bf16(aq[ks], bf_, S[nt], 0, 0, 0);
            }
        // P = exp2(S*scl), write to wave-private p_s (swizzled, conflict-free)
        for (int nt = 0; nt < 4; ++nt)
            for (int r = 0; r < 4; ++r) {
                float p = exp2f(S[nt][r] * SCL);
                p_s[w * 1024 + swz(quad * 4 + r, 2 * nt + (ln >> 3)) + (ln & 7)] = f2b(p);
            }
        short8 ap0 = *(const short8*)&p_s[w * 1024 + swz(ln, quad)];
        short8 ap1 = *(const short8*)&p_s[w * 1024 + swz(ln, 4 + quad)];
        // l += P @ m01  (masked row-sum, lands exactly in C-layout rows)
        lacc = __builtin_amdgcn_mfma_f32_16x16x32_bf16(ap0, mf0, lacc, 0, 0, 0);
        lacc = __builtin_amdgcn_mfma_f32_16x16x32_bf16(ap1, mf1, lacc, 0, 0, 0);
        // O += P @ V  (masked V rows are zero)
        for (int nt = 0; nt < 4; ++nt) {
            short8 bv0 = *(const short8*)&v_s[cur][swz(nt * 16 + ln, quad)];
            Oa[nt] = __builtin_amdgcn_mfma_f32_16x16x32_bf16(ap0, bv0, Oa[nt], 0, 0, 0);
            short8 bv1 = *(const short8*)&v_s[cur][swz(nt * 16 + ln, 4 + quad)];
            Oa[nt] = __builtin_amdgcn_mfma_f32_16x16x32_bf16(ap1, bv1, Oa[nt], 0, 0, 0);
        }
        __syncthreads();   // k_s/v_s swap + prefetch drain
    }

    for (int r = 0; r < 4; ++r) {
        int qrow = q0 + w * 16 + quad * 4 + r;
        float inv = mask[b * T + qrow] ? 1.f / lacc[r] : 0.f;
        for (int nt = 0; nt < 4; ++nt)
            O[(size_t)(b * T + qrow) * E + h * 64 + nt * 16 + ln] = f2b(Oa[nt][r] * inv);
    }
}

// ---------------------------------------------------------------------------
// LayerNorm(a + r): mean over E, std ddof=1, y=(v-mean)/(sd+eps)*g+b.
// ---------------------------------------------------------------------------
template <int R_F32, int O_F32>
__global__ __launch_bounds__(256, 4)
void ln_residual(const unsigned short* __restrict__ A,
                 const void* __restrict__ R,
                 const float* __restrict__ G,
                 const float* __restrict__ Bt,
                 void* __restrict__ Y, int E)
{
    const int row = blockIdx.x;
    const int tid = threadIdx.x;
    size_t base = (size_t)row * E + tid * 4;
    u16x4 a4 = *(const u16x4*)(A + base);
    float rv[4];
    if (R_F32) {
        f32x4 r4 = *(const f32x4*)((const float*)R + base);
        for (int j = 0; j < 4; ++j) rv[j] = r4[j];
    } else {
        u16x4 r4 = *(const u16x4*)((const unsigned short*)R + base);
        for (int j = 0; j < 4; ++j) rv[j] = b2f(r4[j]);
    }
    float v[4]; float s = 0.f, sq = 0.f;
    for (int j = 0; j < 4; ++j) {
        v[j] = b2f(a4[j]) + rv[j];
        s += v[j]; sq += v[j] * v[j];
    }
    for (int o = 32; o; o >>= 1) {
        s  += __shfl_xor(s, o, 64);
        sq += __shfl_xor(sq, o, 64);
    }
    __shared__ float red[8];
    int w = tid >> 6, lane = tid & 63;
    if (lane == 0) { red[w] = s; red[4 + w] = sq; }
    __syncthreads();
    s  = red[0] + red[1] + red[2] + red[3];
    sq = red[4] + red[5] + red[6] + red[7];
    float mean = s / E;
    float var  = (sq - s * mean) / (E - 1);      // ddof=1
    var = fmaxf(var, 0.f);
    float inv = 1.f / (sqrtf(var) + 1e-5f);
    f32x4 g4 = *(const f32x4*)(G + tid * 4);
    f32x4 b4 = *(const f32x4*)(Bt + tid * 4);
    if (O_F32) {
        f32x4 o4;
        for (int j = 0; j < 4; ++j)
            o4[j] = (v[j] - mean) * inv * g4[j] + b4[j];
        *(f32x4*)((float*)Y + base) = o4;
    } else {
        u16x4 o4;
        for (int j = 0; j < 4; ++j)
            o4[j] = f2b((v[j] - mean) * inv * g4[j] + b4[j]);
        *(u16x4*)((unsigned short*)Y + base) = o4;
    }
}

// ---------------------------------------------------------------------------
extern "C" void kernel_launch(void* const* d_in, const int* in_sizes, int n_in,
                              void* d_out, int out_size, void* d_ws, size_t ws_size,
                              hipStream_t stream)
{
    const int B = 4, T = 2048, E = 1024, F = 4096, H = 16;
    const int M = B * T;

    const float* x  = (const float*)d_in[0];
    const int* mask = (const int*)d_in[1];
    const float* Wq = (const float*)d_in[2];
    const float* Wk = (const float*)d_in[3];
    const float* Wv = (const float*)d_in[4];
    const float* Wo = (const float*)d_in[5];
    const float* w1 = (const float*)d_in[6];
    const float* b1 = (const float*)d_in[7];
    const float* w2 = (const float*)d_in[8];
    const float* b2 = (const float*)d_in[9];
    const float* lg = (const float*)d_in[10];
    const float* lb = (const float*)d_in[11];
    float* out = (float*)d_out;

    char* ws = (char*)d_ws;
    const size_t MB = 1024 * 1024;
    unsigned short* xb  = (unsigned short*)(ws);            // 16 MB
    unsigned short* q   = (unsigned short*)(ws + 16 * MB);  // 16 MB
    unsigned short* kk  = (unsigned short*)(ws + 32 * MB);  // 16 MB
    unsigned short* vt  = (unsigned short*)(ws + 48 * MB);  // 16 MB  [B][H][64][T]
    unsigned short* ctx = (unsigned short*)(ws + 64 * MB);  // 16 MB
    unsigned short* hh  = (unsigned short*)(ws + 80 * MB);  // 16 MB (alive after flash)
    unsigned short* mbf = hh;                                // m01 bf16 [B][T], dead before hh
    unsigned short* ff1 = (unsigned short*)(ws);            // 64 MB overlays xb/q/kk/vt (dead)
    unsigned short* ff2 = ctx;                              // ctx dead by then
    unsigned short* att = q;                                // q dead after attention
    unsigned short* Wqb = (unsigned short*)(ws + 96 * MB);  // Wq/Wk/Wv CONTIGUOUS = [3072][1024]
    unsigned short* Wkb = (unsigned short*)(ws + 98 * MB);
    unsigned short* Wvb = (unsigned short*)(ws + 100 * MB);
    unsigned short* Wob = (unsigned short*)(ws + 102 * MB);
    unsigned short* w1b = (unsigned short*)(ws + 104 * MB); // 8 MB
    unsigned short* w2b = (unsigned short*)(ws + 112 * MB); // 8 MB -> 120 MB total

    dim3 blk(256);
    dim3 g512(512);

    // fused casts: x, Wq, Wk, Wv, Wo, w1, w2 (block counts: n_elems/1024)
    CastArgs ca;
    ca.src[0] = x;  ca.dst[0] = xb;
    ca.src[1] = Wq; ca.dst[1] = Wqb;
    ca.src[2] = Wk; ca.dst[2] = Wkb;
    ca.src[3] = Wv; ca.dst[3] = Wvb;
    ca.src[4] = Wo; ca.dst[4] = Wob;
    ca.src[5] = w1; ca.dst[5] = w1b;
    ca.src[6] = w2; ca.dst[6] = w2b;
    int blks[7] = { M * E / 1024, E * E / 1024, E * E / 1024, E * E / 1024,
                    E * E / 1024, F * E / 1024, F * E / 1024 };
    ca.blkcum[0] = 0;
    for (int i = 0; i < 7; ++i) ca.blkcum[i + 1] = ca.blkcum[i] + blks[i];
    cast_all<<<dim3(ca.blkcum[7]), blk, 0, stream>>>(ca);
    mask_bf16<<<dim3(M / 256), blk, 0, stream>>>(mask, mbf, M);

    // fused QKV: N=3072 (Wqb|Wkb|Wvb contiguous); seg 0->q, 1->kk, 2->vt
    gemm_db<0, 0, 1><<<dim3(3072 / 128, M / 128), blk, 0, stream>>>(
        xb, Wqb, nullptr, mask, q, kk, vt, M, 3072, E);
    flash_attn3<<<dim3((T / 128) * H * B), g512, 0, stream>>>(q, kk, vt, mbf, mask, ctx, T, H, E);
    gemm_db<0, 0, 0><<<dim3(E / 128, M / 128), blk, 0, stream>>>(
        ctx, Wob, nullptr, nullptr, att, nullptr, nullptr, M, E, E);
    ln_residual<1, 0><<<dim3(M), blk, 0, stream>>>(att, x, lg, lb, hh, E);
    gemm_db<1, 1, 0><<<dim3(F / 128, M / 128), blk, 0, stream>>>(
        hh, w1b, b1, nullptr, ff1, nullptr, nullptr, M, F, E);
    gemm_db<1, 0, 0><<<dim3(E / 128, M / 128), blk, 0, stream>>>(
        ff1, w2b, b2, nullptr, ff2, nullptr, nullptr, M, E, F);
    ln_residual<0, 1><<<dim3(M), blk, 0, stream>>>(ff2, hh, lg, lb, out, E);
}

// Round 6
// 513.985 us; speedup vs baseline: 1.1951x; 1.0132x over previous
//
#include <hip/hip_runtime.h>
#include <hip/hip_bf16.h>

// ---------------------------------------------------------------------------
// EncoderBlock: B=4 T=2048 E=1024 H=16 hd=64 F=4096. fp32 in/out, bf16 MFMA.
// R10: flash LDS 48->40KB (Q direct->regs, P processed in two 32-key halves,
// 1KB/wave bank-balanced half-buffer) -> 4 blk/CU, grid 1024 = ONE full
// round (R9's 1.33 rounds = the 67% utilization cap). launch_bounds(512,8)
// caps VGPR at 64 (R6 used 56). Softmax scale folded into QKV q-epilogue.
// GEMM/LN/casts = R9 (measured best).
// ---------------------------------------------------------------------------

typedef __attribute__((ext_vector_type(8))) short  short8;   // 8 bf16 = 16B
typedef __attribute__((ext_vector_type(4))) float  f32x4;
typedef __attribute__((ext_vector_type(4))) int    i32x4;
typedef __attribute__((ext_vector_type(4))) unsigned short u16x4;     // 8B

__device__ inline float b2f(unsigned short u) {
    unsigned int x = ((unsigned int)u) << 16;
    return __builtin_bit_cast(float, x);
}
__device__ inline unsigned short f2b(float f) {
    return __builtin_bit_cast(unsigned short, __float2bfloat16(f));
}

// async global->LDS, 16B/lane (m97 fast path)
__device__ inline void llds16(const unsigned short* g, unsigned short* l) {
    __builtin_amdgcn_global_load_lds(
        (const __attribute__((address_space(1))) unsigned int*)g,
        (__attribute__((address_space(3))) unsigned int*)l, 16, 0, 0);
}

// swizzled element offset of 16B-block (row, col8) in a 64-col bf16 tile
__device__ inline int swz(int row, int col8) {
    return (row << 6) + (((col8 ^ (row >> 1)) & 7) << 3);
}

// ---------------------------------------------------------------------------
// fused f32 -> bf16 cast over 7 arrays (x, Wq, Wk, Wv, Wo, w1, w2).
// ---------------------------------------------------------------------------
struct CastArgs {
    const float* src[7];
    unsigned short* dst[7];
    int blkcum[8];          // cumulative block counts
};

__global__ __launch_bounds__(256)
void cast_all(CastArgs a)
{
    int blk = blockIdx.x;
    int s = 0;
    while (blk >= a.blkcum[s + 1]) ++s;     // uniform per block, <=6 iters
    int i = (blk - a.blkcum[s]) * 256 + threadIdx.x;
    f32x4 v = *(const f32x4*)(a.src[s] + (size_t)i * 4);
    u16x4 o;
    for (int j = 0; j < 4; ++j) o[j] = f2b(v[j]);
    *(u16x4*)(a.dst[s] + (size_t)i * 4) = o;
}

__global__ __launch_bounds__(256)
void mask_bf16(const int* __restrict__ m, unsigned short* __restrict__ mb, int n)
{
    int i = blockIdx.x * 256 + threadIdx.x;
    if (i < n) mb[i] = m[i] ? (unsigned short)0x3F80 : (unsigned short)0;  // bf16 1.0/0.0
}

// ---------------------------------------------------------------------------
// gemm_db: C(M,N) = A(M,K) @ W(N,K)^T [+bias][+relu], bf16, fp32 accum.
// 128x128 tile, BK=64, 4 waves, double-buffered LDS, counted vmcnt(8):
// loads stay in flight across barriers (no drain). QKV=1: N=3072 fused;
// seg = bn>>3: 0->q (pre-scaled by 0.125*log2e for flash), 1->kk,
// 2->vt (transposed [b][h][d][t], masked rows zeroed).
// ---------------------------------------------------------------------------
template <int BIAS, int RELU, int QKV>
__global__ __launch_bounds__(256, 2)
void gemm_db(const unsigned short* __restrict__ A,
             const unsigned short* __restrict__ W,
             const float* __restrict__ bias,
             const int* __restrict__ mask,
             unsigned short* __restrict__ C0,
             unsigned short* __restrict__ C1,
             unsigned short* __restrict__ C2,
             int M, int N, int K)
{
    __shared__ __attribute__((aligned(16))) unsigned short a_s[2][128 * 64];
    __shared__ __attribute__((aligned(16))) unsigned short b_s[2][128 * 64];

    const int tid  = threadIdx.x;
    const int lane = tid & 63;
    const int w    = tid >> 6;
    const int ln   = lane & 15;
    const int quad = lane >> 4;
    const int wm   = w >> 1, wn = w & 1;
    const int bm   = blockIdx.y, bn = blockIdx.x;

    f32x4 acc[4][4] = {};

    const unsigned short* Abase = A + (size_t)(bm * 128) * K;
    const unsigned short* Wbase = W + (size_t)(bn * 128) * K;

    auto stage = [&](int buf, int kt) {
#pragma unroll
        for (int i = 0; i < 4; ++i) {
            int e   = i * 256 + tid;          // 16B block index 0..1023
            int row = e >> 3;
            int c8  = (e & 7) ^ ((e >> 4) & 7);   // source permutation = swizzle
            llds16(Abase + (size_t)row * K + kt * 64 + c8 * 8, &a_s[buf][e * 8]);
            llds16(Wbase + (size_t)row * K + kt * 64 + c8 * 8, &b_s[buf][e * 8]);
        }
    };

    const int nkt = K >> 6;                   // >= 16 for all our shapes
    stage(0, 0);
    stage(1, 1);
    int cur = 0;
    for (int kt = 0; kt < nkt; ++kt) {
        // wait for tile kt (8 newer loads = tile kt+1 stay in flight)
        if (kt + 1 < nkt) asm volatile("s_waitcnt vmcnt(8)" ::: "memory");
        else              asm volatile("s_waitcnt vmcnt(0)" ::: "memory");
        asm volatile("s_barrier" ::: "memory");      // tile kt visible block-wide
#pragma unroll
        for (int ks = 0; ks < 2; ++ks) {
            short8 af[4], bf_[4];
#pragma unroll
            for (int mt = 0; mt < 4; ++mt)
                af[mt] = *(const short8*)&a_s[cur][swz(wm * 64 + mt * 16 + ln, ks * 4 + quad)];
#pragma unroll
            for (int nt = 0; nt < 4; ++nt)
                bf_[nt] = *(const short8*)&b_s[cur][swz(wn * 64 + nt * 16 + ln, ks * 4 + quad)];
#pragma unroll
            for (int mt = 0; mt < 4; ++mt)
#pragma unroll
                for (int nt = 0; nt < 4; ++nt)
                    acc[mt][nt] = __builtin_amdgcn_mfma_f32_16x16x32_bf16(
                        af[mt], bf_[nt], acc[mt][nt], 0, 0, 0);
        }
        asm volatile("s_barrier" ::: "memory");      // all reads of buf[cur] done
        if (kt + 2 < nkt) stage(cur, kt + 2);        // overwrite old buffer
        cur ^= 1;
    }

    // C/D layout: col=lane&15, row=quad*4+reg
    if (QKV) {
        const int seg = bn >> 3;              // 0=q 1=kk 2=vt
        const int lbn = bn & 7;
        if (seg < 2) {
            unsigned short* C = seg == 0 ? C0 : C1;
            const float scl = seg == 0 ? 0.18033688f : 1.0f;   // 0.125*log2(e)
#pragma unroll
            for (int nt = 0; nt < 4; ++nt) {
                int col = lbn * 128 + wn * 64 + nt * 16 + ln;
#pragma unroll
                for (int mt = 0; mt < 4; ++mt) {
                    int row0 = bm * 128 + wm * 64 + mt * 16 + quad * 4;
#pragma unroll
                    for (int r = 0; r < 4; ++r)
                        C[(size_t)(row0 + r) * 1024 + col] = f2b(acc[mt][nt][r] * scl);
                }
            }
        } else {
            const int T2 = 2048, H2 = 16;
#pragma unroll
            for (int mt = 0; mt < 4; ++mt) {
                int row0 = bm * 128 + wm * 64 + mt * 16 + quad * 4;
                int bb = row0 >> 11, t0 = row0 & 2047;
                i32x4 mi = *(const i32x4*)&mask[bb * 2048 + t0];
#pragma unroll
                for (int nt = 0; nt < 4; ++nt) {
                    int col = lbn * 128 + wn * 64 + nt * 16 + ln;
                    int hh2 = col >> 6, d = col & 63;
                    u16x4 o;
#pragma unroll
                    for (int r = 0; r < 4; ++r)
                        o[r] = mi[r] ? f2b(acc[mt][nt][r]) : (unsigned short)0;
                    *(u16x4*)(C2 + ((size_t)((bb * H2 + hh2) * 64 + d)) * T2 + t0) = o;
                }
            }
        }
    } else {
#pragma unroll
        for (int nt = 0; nt < 4; ++nt) {
            int col = bn * 128 + wn * 64 + nt * 16 + ln;
            float bv = 0.f;
            if (BIAS) bv = bias[col];
#pragma unroll
            for (int mt = 0; mt < 4; ++mt) {
                int row0 = bm * 128 + wm * 64 + mt * 16 + quad * 4;
#pragma unroll
                for (int r = 0; r < 4; ++r) {
                    float v = acc[mt][nt][r] + bv;
                    if (RELU) v = v > 0.f ? v : 0.f;
                    C0[(size_t)(row0 + r) * N + col] = f2b(v);
                }
            }
        }
    }
}

// ---------------------------------------------------------------------------
// Flash attention v6. Block = 8 waves = one (b,h,128 q); wave = 16 q.
// LDS 40KB (k_s/v_s dbuf 32KB + 1KB/wave P half-buffer) -> 4 blk/CU;
// grid 1024 = exactly one full-occupancy round (R9 ran 1.33 rounds).
// Q direct global->regs (pre-scaled in QKV epilogue: p = exp2(S) directly).
// P processed as two 32-key halves; half-buffer bank-balanced by XOR'ing the
// key-slot with the q-row (8 words/bank on the b128 read = conflict floor).
// ph is wave-private: per-wave DS FIFO ordering makes write->read->overwrite
// safe without barriers. Maskless k-loop as before (V rows zeroed, l = P@m01).
// ---------------------------------------------------------------------------
__global__ __launch_bounds__(512, 8)
void flash_attn6(const unsigned short* __restrict__ Q,
                 const unsigned short* __restrict__ K,
                 const unsigned short* __restrict__ Vt,
                 const unsigned short* __restrict__ mb,
                 const int* __restrict__ mask,
                 unsigned short* __restrict__ O,
                 int T, int H, int E)
{
    __shared__ __attribute__((aligned(16))) unsigned short k_s[2][64 * 64];
    __shared__ __attribute__((aligned(16))) unsigned short v_s[2][64 * 64];
    __shared__ __attribute__((aligned(16))) unsigned short p_s[8][512];

    // bijective XCD swizzle: 1024 blocks % 8 == 0; XCD x owns 8 (b,h) panels
    const int ord = blockIdx.x;
    const int wg  = (ord & 7) * 128 + (ord >> 3);
    const int qt  = wg & 15;          // T/128 = 16
    const int h   = (wg >> 4) & 15;   // H  = 16
    const int b   = wg >> 8;          // B  = 4

    const int tid  = threadIdx.x;
    const int w    = tid >> 6;
    const int lane = tid & 63;
    const int ln   = lane & 15;
    const int quad = lane >> 4;
    const int q0   = qt * 128;
    const unsigned short* vt_b = Vt + (size_t)(b * H + h) * 64 * T;

    // Q fragments direct from global (row = own q, cols quad*8.. / 32+quad*8..)
    const unsigned short* qp = Q + (size_t)(b * T + q0 + w * 16 + ln) * E + h * 64;
    short8 aq[2];
    aq[0] = *(const short8*)(qp + quad * 8);
    aq[1] = *(const short8*)(qp + 32 + quad * 8);

    // stage K/V tile 0 (512 thr x 16B = one full 64x64 tile each)
    {
        int e = tid;
        int row = e >> 3;
        int c8  = (e & 7) ^ ((e >> 4) & 7);
        llds16(K + (size_t)(b * T + row) * E + h * 64 + c8 * 8, &k_s[0][e * 8]);
        llds16(vt_b + (size_t)row * T + c8 * 8, &v_s[0][e * 8]);
    }
    __syncthreads();

    f32x4 Oa[4] = {};
    f32x4 lacc = {};
    unsigned short* ph = &p_s[w][0];
    const int rdoff = ln * 32 + (((quad ^ (ln >> 1)) & 3) << 3);  // b128 read base

    const int nkb = T >> 6;
    for (int kb = 0; kb < nkb; ++kb) {
        const int cur = kb & 1;
        if (kb + 1 < nkb) {     // async prefetch next K/V tile; drains at barrier
            int e = tid;
            int row = e >> 3;
            int c8  = (e & 7) ^ ((e >> 4) & 7);
            llds16(K + (size_t)(b * T + (kb + 1) * 64 + row) * E + h * 64 + c8 * 8,
                   &k_s[cur ^ 1][e * 8]);
            llds16(vt_b + (size_t)row * T + (kb + 1) * 64 + c8 * 8,
                   &v_s[cur ^ 1][e * 8]);
        }
        // m01 B-frags (16B/lane, L2-hot)
        short8 mf0 = *(const short8*)&mb[b * T + kb * 64 + quad * 8];
        short8 mf1 = *(const short8*)&mb[b * T + kb * 64 + 32 + quad * 8];

        // S = Q K^T : 8 MFMAs  (Q pre-scaled, so p = exp2(S) directly)
        f32x4 S[4] = {};
        for (int ks = 0; ks < 2; ++ks)
            for (int nt = 0; nt < 4; ++nt) {
                short8 bf_ = *(const short8*)&k_s[cur][swz(nt * 16 + ln, ks * 4 + quad)];
                S[nt] = __builtin_amdgcn_mfma_f32_16x16x32_bf16(aq[ks], bf_, S[nt], 0, 0, 0);
            }

        // ---- half A: keys 0..31 (S[0],S[1]) ----
        for (int nt = 0; nt < 2; ++nt)
            for (int r = 0; r < 4; ++r) {
                float p = exp2f(S[nt][r]);
                int qr = quad * 4 + r;
                int k8 = 2 * nt + (ln >> 3);
                ph[qr * 32 + (((k8 ^ (qr >> 1)) & 3) << 3) + (ln & 7)] = f2b(p);
            }
        short8 ap0 = *(const short8*)&ph[rdoff];
        lacc = __builtin_amdgcn_mfma_f32_16x16x32_bf16(ap0, mf0, lacc, 0, 0, 0);
        for (int nt = 0; nt < 4; ++nt) {
            short8 bv0 = *(const short8*)&v_s[cur][swz(nt * 16 + ln, quad)];
            Oa[nt] = __builtin_amdgcn_mfma_f32_16x16x32_bf16(ap0, bv0, Oa[nt], 0, 0, 0);
        }
        // ---- half B: keys 32..63 (S[2],S[3]) ----
        for (int nt = 0; nt < 2; ++nt)
            for (int r = 0; r < 4; ++r) {
                float p = exp2f(S[2 + nt][r]);
                int qr = quad * 4 + r;
                int k8 = 2 * nt + (ln >> 3);
                ph[qr * 32 + (((k8 ^ (qr >> 1)) & 3) << 3) + (ln & 7)] = f2b(p);
            }
        short8 ap1 = *(const short8*)&ph[rdoff];
        lacc = __builtin_amdgcn_mfma_f32_16x16x32_bf16(ap1, mf1, lacc, 0, 0, 0);
        for (int nt = 0; nt < 4; ++nt) {
            short8 bv1 = *(const short8*)&v_s[cur][swz(nt * 16 + ln, 4 + quad)];
            Oa[nt] = __builtin_amdgcn_mfma_f32_16x16x32_bf16(ap1, bv1, Oa[nt], 0, 0, 0);
        }
        __syncthreads();   // k_s/v_s swap + prefetch drain
    }

    for (int r = 0; r < 4; ++r) {
        int qrow = q0 + w * 16 + quad * 4 + r;
        float inv = mask[b * T + qrow] ? 1.f / lacc[r] : 0.f;
        for (int nt = 0; nt < 4; ++nt)
            O[(size_t)(b * T + qrow) * E + h * 64 + nt * 16 + ln] = f2b(Oa[nt][r] * inv);
    }
}

// ---------------------------------------------------------------------------
// LayerNorm(a + r): mean over E, std ddof=1, y=(v-mean)/(sd+eps)*g+b.
// ---------------------------------------------------------------------------
template <int R_F32, int O_F32>
__global__ __launch_bounds__(256, 4)
void ln_residual(const unsigned short* __restrict__ A,
                 const void* __restrict__ R,
                 const float* __restrict__ G,
                 const float* __restrict__ Bt,
                 void* __restrict__ Y, int E)
{
    const int row = blockIdx.x;
    const int tid = threadIdx.x;
    size_t base = (size_t)row * E + tid * 4;
    u16x4 a4 = *(const u16x4*)(A + base);
    float rv[4];
    if (R_F32) {
        f32x4 r4 = *(const f32x4*)((const float*)R + base);
        for (int j = 0; j < 4; ++j) rv[j] = r4[j];
    } else {
        u16x4 r4 = *(const u16x4*)((const unsigned short*)R + base);
        for (int j = 0; j < 4; ++j) rv[j] = b2f(r4[j]);
    }
    float v[4]; float s = 0.f, sq = 0.f;
    for (int j = 0; j < 4; ++j) {
        v[j] = b2f(a4[j]) + rv[j];
        s += v[j]; sq += v[j] * v[j];
    }
    for (int o = 32; o; o >>= 1) {
        s  += __shfl_xor(s, o, 64);
        sq += __shfl_xor(sq, o, 64);
    }
    __shared__ float red[8];
    int w = tid >> 6, lane = tid & 63;
    if (lane == 0) { red[w] = s; red[4 + w] = sq; }
    __syncthreads();
    s  = red[0] + red[1] + red[2] + red[3];
    sq = red[4] + red[5] + red[6] + red[7];
    float mean = s / E;
    float var  = (sq - s * mean) / (E - 1);      // ddof=1
    var = fmaxf(var, 0.f);
    float inv = 1.f / (sqrtf(var) + 1e-5f);
    f32x4 g4 = *(const f32x4*)(G + tid * 4);
    f32x4 b4 = *(const f32x4*)(Bt + tid * 4);
    if (O_F32) {
        f32x4 o4;
        for (int j = 0; j < 4; ++j)
            o4[j] = (v[j] - mean) * inv * g4[j] + b4[j];
        *(f32x4*)((float*)Y + base) = o4;
    } else {
        u16x4 o4;
        for (int j = 0; j < 4; ++j)
            o4[j] = f2b((v[j] - mean) * inv * g4[j] + b4[j]);
        *(u16x4*)((unsigned short*)Y + base) = o4;
    }
}

// ---------------------------------------------------------------------------
extern "C" void kernel_launch(void* const* d_in, const int* in_sizes, int n_in,
                              void* d_out, int out_size, void* d_ws, size_t ws_size,
                              hipStream_t stream)
{
    const int B = 4, T = 2048, E = 1024, F = 4096, H = 16;
    const int M = B * T;

    const float* x  = (const float*)d_in[0];
    const int* mask = (const int*)d_in[1];
    const float* Wq = (const float*)d_in[2];
    const float* Wk = (const float*)d_in[3];
    const float* Wv = (const float*)d_in[4];
    const float* Wo = (const float*)d_in[5];
    const float* w1 = (const float*)d_in[6];
    const float* b1 = (const float*)d_in[7];
    const float* w2 = (const float*)d_in[8];
    const float* b2 = (const float*)d_in[9];
    const float* lg = (const float*)d_in[10];
    const float* lb = (const float*)d_in[11];
    float* out = (float*)d_out;

    char* ws = (char*)d_ws;
    const size_t MB = 1024 * 1024;
    unsigned short* xb  = (unsigned short*)(ws);            // 16 MB
    unsigned short* q   = (unsigned short*)(ws + 16 * MB);  // 16 MB
    unsigned short* kk  = (unsigned short*)(ws + 32 * MB);  // 16 MB
    unsigned short* vt  = (unsigned short*)(ws + 48 * MB);  // 16 MB  [B][H][64][T]
    unsigned short* ctx = (unsigned short*)(ws + 64 * MB);  // 16 MB
    unsigned short* hh  = (unsigned short*)(ws + 80 * MB);  // 16 MB (alive after flash)
    unsigned short* mbf = hh;                                // m01 bf16 [B][T], dead before hh
    unsigned short* ff1 = (unsigned short*)(ws);            // 64 MB overlays xb/q/kk/vt (dead)
    unsigned short* ff2 = ctx;                              // ctx dead by then
    unsigned short* att = q;                                // q dead after attention
    unsigned short* Wqb = (unsigned short*)(ws + 96 * MB);  // Wq/Wk/Wv CONTIGUOUS = [3072][1024]
    unsigned short* Wkb = (unsigned short*)(ws + 98 * MB);
    unsigned short* Wvb = (unsigned short*)(ws + 100 * MB);
    unsigned short* Wob = (unsigned short*)(ws + 102 * MB);
    unsigned short* w1b = (unsigned short*)(ws + 104 * MB); // 8 MB
    unsigned short* w2b = (unsigned short*)(ws + 112 * MB); // 8 MB -> 120 MB total

    dim3 blk(256);
    dim3 g512(512);

    // fused casts: x, Wq, Wk, Wv, Wo, w1, w2 (block counts: n_elems/1024)
    CastArgs ca;
    ca.src[0] = x;  ca.dst[0] = xb;
    ca.src[1] = Wq; ca.dst[1] = Wqb;
    ca.src[2] = Wk; ca.dst[2] = Wkb;
    ca.src[3] = Wv; ca.dst[3] = Wvb;
    ca.src[4] = Wo; ca.dst[4] = Wob;
    ca.src[5] = w1; ca.dst[5] = w1b;
    ca.src[6] = w2; ca.dst[6] = w2b;
    int blks[7] = { M * E / 1024, E * E / 1024, E * E / 1024, E * E / 1024,
                    E * E / 1024, F * E / 1024, F * E / 1024 };
    ca.blkcum[0] = 0;
    for (int i = 0; i < 7; ++i) ca.blkcum[i + 1] = ca.blkcum[i] + blks[i];
    cast_all<<<dim3(ca.blkcum[7]), blk, 0, stream>>>(ca);
    mask_bf16<<<dim3(M / 256), blk, 0, stream>>>(mask, mbf, M);

    // fused QKV: N=3072 (Wqb|Wkb|Wvb contiguous); seg 0->q (scaled), 1->kk, 2->vt
    gemm_db<0, 0, 1><<<dim3(3072 / 128, M / 128), blk, 0, stream>>>(
        xb, Wqb, nullptr, mask, q, kk, vt, M, 3072, E);
    flash_attn6<<<dim3((T / 128) * H * B), g512, 0, stream>>>(q, kk, vt, mbf, mask, ctx, T, H, E);
    gemm_db<0, 0, 0><<<dim3(E / 128, M / 128), blk, 0, stream>>>(
        ctx, Wob, nullptr, nullptr, att, nullptr, nullptr, M, E, E);
    ln_residual<1, 0><<<dim3(M), blk, 0, stream>>>(att, x, lg, lb, hh, E);
    gemm_db<1, 1, 0><<<dim3(F / 128, M / 128), blk, 0, stream>>>(
        hh, w1b, b1, nullptr, ff1, nullptr, nullptr, M, F, E);
    gemm_db<1, 0, 0><<<dim3(E / 128, M / 128), blk, 0, stream>>>(
        ff1, w2b, b2, nullptr, ff2, nullptr, nullptr, M, E, F);
    ln_residual<0, 1><<<dim3(M), blk, 0, stream>>>(ff2, hh, lg, lb, out, E);
}

// Round 7
// 505.321 us; speedup vs baseline: 1.2156x; 1.0171x over previous
//
#include <hip/hip_runtime.h>
#include <hip/hip_bf16.h>

// ---------------------------------------------------------------------------
// EncoderBlock: B=4 T=2048 E=1024 H=16 hd=64 F=4096. fp32 in/out, bf16 MFMA.
// R11: single change vs R10 -- flash launch_bounds (512,8)->(512,2). R10's
// forced 8-wave/EU cap = 64 unified VGPR/wave made the allocator pick 32
// arch-VGPRs + spill (~10MB scratch writes in-loop: WRITE_SIZE 26624 vs
// 16384 output). Natural allocation (~56, R6 precedent) still fits 8
// waves/SIMD -> keeps the 4 blk/CU one-round occupancy, drops the scratch.
// ---------------------------------------------------------------------------

typedef __attribute__((ext_vector_type(8))) short  short8;   // 8 bf16 = 16B
typedef __attribute__((ext_vector_type(4))) float  f32x4;
typedef __attribute__((ext_vector_type(4))) int    i32x4;
typedef __attribute__((ext_vector_type(4))) unsigned short u16x4;     // 8B

__device__ inline float b2f(unsigned short u) {
    unsigned int x = ((unsigned int)u) << 16;
    return __builtin_bit_cast(float, x);
}
__device__ inline unsigned short f2b(float f) {
    return __builtin_bit_cast(unsigned short, __float2bfloat16(f));
}

// async global->LDS, 16B/lane (m97 fast path)
__device__ inline void llds16(const unsigned short* g, unsigned short* l) {
    __builtin_amdgcn_global_load_lds(
        (const __attribute__((address_space(1))) unsigned int*)g,
        (__attribute__((address_space(3))) unsigned int*)l, 16, 0, 0);
}

// swizzled element offset of 16B-block (row, col8) in a 64-col bf16 tile
__device__ inline int swz(int row, int col8) {
    return (row << 6) + (((col8 ^ (row >> 1)) & 7) << 3);
}

// ---------------------------------------------------------------------------
// fused f32 -> bf16 cast over 7 arrays (x, Wq, Wk, Wv, Wo, w1, w2).
// ---------------------------------------------------------------------------
struct CastArgs {
    const float* src[7];
    unsigned short* dst[7];
    int blkcum[8];          // cumulative block counts
};

__global__ __launch_bounds__(256)
void cast_all(CastArgs a)
{
    int blk = blockIdx.x;
    int s = 0;
    while (blk >= a.blkcum[s + 1]) ++s;     // uniform per block, <=6 iters
    int i = (blk - a.blkcum[s]) * 256 + threadIdx.x;
    f32x4 v = *(const f32x4*)(a.src[s] + (size_t)i * 4);
    u16x4 o;
    for (int j = 0; j < 4; ++j) o[j] = f2b(v[j]);
    *(u16x4*)(a.dst[s] + (size_t)i * 4) = o;
}

__global__ __launch_bounds__(256)
void mask_bf16(const int* __restrict__ m, unsigned short* __restrict__ mb, int n)
{
    int i = blockIdx.x * 256 + threadIdx.x;
    if (i < n) mb[i] = m[i] ? (unsigned short)0x3F80 : (unsigned short)0;  // bf16 1.0/0.0
}

// ---------------------------------------------------------------------------
// gemm_db: C(M,N) = A(M,K) @ W(N,K)^T [+bias][+relu], bf16, fp32 accum.
// 128x128 tile, BK=64, 4 waves, double-buffered LDS, counted vmcnt(8):
// loads stay in flight across barriers (no drain). QKV=1: N=3072 fused;
// seg = bn>>3: 0->q (pre-scaled by 0.125*log2e for flash), 1->kk,
// 2->vt (transposed [b][h][d][t], masked rows zeroed).
// ---------------------------------------------------------------------------
template <int BIAS, int RELU, int QKV>
__global__ __launch_bounds__(256, 2)
void gemm_db(const unsigned short* __restrict__ A,
             const unsigned short* __restrict__ W,
             const float* __restrict__ bias,
             const int* __restrict__ mask,
             unsigned short* __restrict__ C0,
             unsigned short* __restrict__ C1,
             unsigned short* __restrict__ C2,
             int M, int N, int K)
{
    __shared__ __attribute__((aligned(16))) unsigned short a_s[2][128 * 64];
    __shared__ __attribute__((aligned(16))) unsigned short b_s[2][128 * 64];

    const int tid  = threadIdx.x;
    const int lane = tid & 63;
    const int w    = tid >> 6;
    const int ln   = lane & 15;
    const int quad = lane >> 4;
    const int wm   = w >> 1, wn = w & 1;
    const int bm   = blockIdx.y, bn = blockIdx.x;

    f32x4 acc[4][4] = {};

    const unsigned short* Abase = A + (size_t)(bm * 128) * K;
    const unsigned short* Wbase = W + (size_t)(bn * 128) * K;

    auto stage = [&](int buf, int kt) {
#pragma unroll
        for (int i = 0; i < 4; ++i) {
            int e   = i * 256 + tid;          // 16B block index 0..1023
            int row = e >> 3;
            int c8  = (e & 7) ^ ((e >> 4) & 7);   // source permutation = swizzle
            llds16(Abase + (size_t)row * K + kt * 64 + c8 * 8, &a_s[buf][e * 8]);
            llds16(Wbase + (size_t)row * K + kt * 64 + c8 * 8, &b_s[buf][e * 8]);
        }
    };

    const int nkt = K >> 6;                   // >= 16 for all our shapes
    stage(0, 0);
    stage(1, 1);
    int cur = 0;
    for (int kt = 0; kt < nkt; ++kt) {
        // wait for tile kt (8 newer loads = tile kt+1 stay in flight)
        if (kt + 1 < nkt) asm volatile("s_waitcnt vmcnt(8)" ::: "memory");
        else              asm volatile("s_waitcnt vmcnt(0)" ::: "memory");
        asm volatile("s_barrier" ::: "memory");      // tile kt visible block-wide
#pragma unroll
        for (int ks = 0; ks < 2; ++ks) {
            short8 af[4], bf_[4];
#pragma unroll
            for (int mt = 0; mt < 4; ++mt)
                af[mt] = *(const short8*)&a_s[cur][swz(wm * 64 + mt * 16 + ln, ks * 4 + quad)];
#pragma unroll
            for (int nt = 0; nt < 4; ++nt)
                bf_[nt] = *(const short8*)&b_s[cur][swz(wn * 64 + nt * 16 + ln, ks * 4 + quad)];
#pragma unroll
            for (int mt = 0; mt < 4; ++mt)
#pragma unroll
                for (int nt = 0; nt < 4; ++nt)
                    acc[mt][nt] = __builtin_amdgcn_mfma_f32_16x16x32_bf16(
                        af[mt], bf_[nt], acc[mt][nt], 0, 0, 0);
        }
        asm volatile("s_barrier" ::: "memory");      // all reads of buf[cur] done
        if (kt + 2 < nkt) stage(cur, kt + 2);        // overwrite old buffer
        cur ^= 1;
    }

    // C/D layout: col=lane&15, row=quad*4+reg
    if (QKV) {
        const int seg = bn >> 3;              // 0=q 1=kk 2=vt
        const int lbn = bn & 7;
        if (seg < 2) {
            unsigned short* C = seg == 0 ? C0 : C1;
            const float scl = seg == 0 ? 0.18033688f : 1.0f;   // 0.125*log2(e)
#pragma unroll
            for (int nt = 0; nt < 4; ++nt) {
                int col = lbn * 128 + wn * 64 + nt * 16 + ln;
#pragma unroll
                for (int mt = 0; mt < 4; ++mt) {
                    int row0 = bm * 128 + wm * 64 + mt * 16 + quad * 4;
#pragma unroll
                    for (int r = 0; r < 4; ++r)
                        C[(size_t)(row0 + r) * 1024 + col] = f2b(acc[mt][nt][r] * scl);
                }
            }
        } else {
            const int T2 = 2048, H2 = 16;
#pragma unroll
            for (int mt = 0; mt < 4; ++mt) {
                int row0 = bm * 128 + wm * 64 + mt * 16 + quad * 4;
                int bb = row0 >> 11, t0 = row0 & 2047;
                i32x4 mi = *(const i32x4*)&mask[bb * 2048 + t0];
#pragma unroll
                for (int nt = 0; nt < 4; ++nt) {
                    int col = lbn * 128 + wn * 64 + nt * 16 + ln;
                    int hh2 = col >> 6, d = col & 63;
                    u16x4 o;
#pragma unroll
                    for (int r = 0; r < 4; ++r)
                        o[r] = mi[r] ? f2b(acc[mt][nt][r]) : (unsigned short)0;
                    *(u16x4*)(C2 + ((size_t)((bb * H2 + hh2) * 64 + d)) * T2 + t0) = o;
                }
            }
        }
    } else {
#pragma unroll
        for (int nt = 0; nt < 4; ++nt) {
            int col = bn * 128 + wn * 64 + nt * 16 + ln;
            float bv = 0.f;
            if (BIAS) bv = bias[col];
#pragma unroll
            for (int mt = 0; mt < 4; ++mt) {
                int row0 = bm * 128 + wm * 64 + mt * 16 + quad * 4;
#pragma unroll
                for (int r = 0; r < 4; ++r) {
                    float v = acc[mt][nt][r] + bv;
                    if (RELU) v = v > 0.f ? v : 0.f;
                    C0[(size_t)(row0 + r) * N + col] = f2b(v);
                }
            }
        }
    }
}

// ---------------------------------------------------------------------------
// Flash attention v6b. Block = 8 waves = one (b,h,128 q); wave = 16 q.
// LDS 40KB (k_s/v_s dbuf 32KB + 1KB/wave P half-buffer) -> 4 blk/CU;
// grid 1024 = exactly one full-occupancy round. Q direct global->regs
// (pre-scaled in QKV epilogue: p = exp2(S) directly). P processed as two
// 32-key halves; half-buffer bank-balanced by XOR'ing key-slot with q-row.
// ph wave-private (per-wave DS FIFO => no barrier needed around it).
// launch_bounds(512,2): natural VGPR (~56) fits 8 waves/SIMD, no spill.
// ---------------------------------------------------------------------------
__global__ __launch_bounds__(512, 2)
void flash_attn6(const unsigned short* __restrict__ Q,
                 const unsigned short* __restrict__ K,
                 const unsigned short* __restrict__ Vt,
                 const unsigned short* __restrict__ mb,
                 const int* __restrict__ mask,
                 unsigned short* __restrict__ O,
                 int T, int H, int E)
{
    __shared__ __attribute__((aligned(16))) unsigned short k_s[2][64 * 64];
    __shared__ __attribute__((aligned(16))) unsigned short v_s[2][64 * 64];
    __shared__ __attribute__((aligned(16))) unsigned short p_s[8][512];

    // bijective XCD swizzle: 1024 blocks % 8 == 0; XCD x owns 8 (b,h) panels
    const int ord = blockIdx.x;
    const int wg  = (ord & 7) * 128 + (ord >> 3);
    const int qt  = wg & 15;          // T/128 = 16
    const int h   = (wg >> 4) & 15;   // H  = 16
    const int b   = wg >> 8;          // B  = 4

    const int tid  = threadIdx.x;
    const int w    = tid >> 6;
    const int lane = tid & 63;
    const int ln   = lane & 15;
    const int quad = lane >> 4;
    const int q0   = qt * 128;
    const unsigned short* vt_b = Vt + (size_t)(b * H + h) * 64 * T;

    // Q fragments direct from global (row = own q, cols quad*8.. / 32+quad*8..)
    const unsigned short* qp = Q + (size_t)(b * T + q0 + w * 16 + ln) * E + h * 64;
    short8 aq[2];
    aq[0] = *(const short8*)(qp + quad * 8);
    aq[1] = *(const short8*)(qp + 32 + quad * 8);

    // stage K/V tile 0 (512 thr x 16B = one full 64x64 tile each)
    {
        int e = tid;
        int row = e >> 3;
        int c8  = (e & 7) ^ ((e >> 4) & 7);
        llds16(K + (size_t)(b * T + row) * E + h * 64 + c8 * 8, &k_s[0][e * 8]);
        llds16(vt_b + (size_t)row * T + c8 * 8, &v_s[0][e * 8]);
    }
    __syncthreads();

    f32x4 Oa[4] = {};
    f32x4 lacc = {};
    unsigned short* ph = &p_s[w][0];
    const int rdoff = ln * 32 + (((quad ^ (ln >> 1)) & 3) << 3);  // b128 read base

    const int nkb = T >> 6;
    for (int kb = 0; kb < nkb; ++kb) {
        const int cur = kb & 1;
        if (kb + 1 < nkb) {     // async prefetch next K/V tile; drains at barrier
            int e = tid;
            int row = e >> 3;
            int c8  = (e & 7) ^ ((e >> 4) & 7);
            llds16(K + (size_t)(b * T + (kb + 1) * 64 + row) * E + h * 64 + c8 * 8,
                   &k_s[cur ^ 1][e * 8]);
            llds16(vt_b + (size_t)row * T + (kb + 1) * 64 + c8 * 8,
                   &v_s[cur ^ 1][e * 8]);
        }
        // m01 B-frags (16B/lane, L2-hot)
        short8 mf0 = *(const short8*)&mb[b * T + kb * 64 + quad * 8];
        short8 mf1 = *(const short8*)&mb[b * T + kb * 64 + 32 + quad * 8];

        // S = Q K^T : 8 MFMAs  (Q pre-scaled, so p = exp2(S) directly)
        f32x4 S[4] = {};
        for (int ks = 0; ks < 2; ++ks)
            for (int nt = 0; nt < 4; ++nt) {
                short8 bf_ = *(const short8*)&k_s[cur][swz(nt * 16 + ln, ks * 4 + quad)];
                S[nt] = __builtin_amdgcn_mfma_f32_16x16x32_bf16(aq[ks], bf_, S[nt], 0, 0, 0);
            }

        // ---- half A: keys 0..31 (S[0],S[1]) ----
        for (int nt = 0; nt < 2; ++nt)
            for (int r = 0; r < 4; ++r) {
                float p = exp2f(S[nt][r]);
                int qr = quad * 4 + r;
                int k8 = 2 * nt + (ln >> 3);
                ph[qr * 32 + (((k8 ^ (qr >> 1)) & 3) << 3) + (ln & 7)] = f2b(p);
            }
        short8 ap0 = *(const short8*)&ph[rdoff];
        lacc = __builtin_amdgcn_mfma_f32_16x16x32_bf16(ap0, mf0, lacc, 0, 0, 0);
        for (int nt = 0; nt < 4; ++nt) {
            short8 bv0 = *(const short8*)&v_s[cur][swz(nt * 16 + ln, quad)];
            Oa[nt] = __builtin_amdgcn_mfma_f32_16x16x32_bf16(ap0, bv0, Oa[nt], 0, 0, 0);
        }
        // ---- half B: keys 32..63 (S[2],S[3]) ----
        for (int nt = 0; nt < 2; ++nt)
            for (int r = 0; r < 4; ++r) {
                float p = exp2f(S[2 + nt][r]);
                int qr = quad * 4 + r;
                int k8 = 2 * nt + (ln >> 3);
                ph[qr * 32 + (((k8 ^ (qr >> 1)) & 3) << 3) + (ln & 7)] = f2b(p);
            }
        short8 ap1 = *(const short8*)&ph[rdoff];
        lacc = __builtin_amdgcn_mfma_f32_16x16x32_bf16(ap1, mf1, lacc, 0, 0, 0);
        for (int nt = 0; nt < 4; ++nt) {
            short8 bv1 = *(const short8*)&v_s[cur][swz(nt * 16 + ln, 4 + quad)];
            Oa[nt] = __builtin_amdgcn_mfma_f32_16x16x32_bf16(ap1, bv1, Oa[nt], 0, 0, 0);
        }
        __syncthreads();   // k_s/v_s swap + prefetch drain
    }

    for (int r = 0; r < 4; ++r) {
        int qrow = q0 + w * 16 + quad * 4 + r;
        float inv = mask[b * T + qrow] ? 1.f / lacc[r] : 0.f;
        for (int nt = 0; nt < 4; ++nt)
            O[(size_t)(b * T + qrow) * E + h * 64 + nt * 16 + ln] = f2b(Oa[nt][r] * inv);
    }
}

// ---------------------------------------------------------------------------
// LayerNorm(a + r): mean over E, std ddof=1, y=(v-mean)/(sd+eps)*g+b.
// ---------------------------------------------------------------------------
template <int R_F32, int O_F32>
__global__ __launch_bounds__(256, 4)
void ln_residual(const unsigned short* __restrict__ A,
                 const void* __restrict__ R,
                 const float* __restrict__ G,
                 const float* __restrict__ Bt,
                 void* __restrict__ Y, int E)
{
    const int row = blockIdx.x;
    const int tid = threadIdx.x;
    size_t base = (size_t)row * E + tid * 4;
    u16x4 a4 = *(const u16x4*)(A + base);
    float rv[4];
    if (R_F32) {
        f32x4 r4 = *(const f32x4*)((const float*)R + base);
        for (int j = 0; j < 4; ++j) rv[j] = r4[j];
    } else {
        u16x4 r4 = *(const u16x4*)((const unsigned short*)R + base);
        for (int j = 0; j < 4; ++j) rv[j] = b2f(r4[j]);
    }
    float v[4]; float s = 0.f, sq = 0.f;
    for (int j = 0; j < 4; ++j) {
        v[j] = b2f(a4[j]) + rv[j];
        s += v[j]; sq += v[j] * v[j];
    }
    for (int o = 32; o; o >>= 1) {
        s  += __shfl_xor(s, o, 64);
        sq += __shfl_xor(sq, o, 64);
    }
    __shared__ float red[8];
    int w = tid >> 6, lane = tid & 63;
    if (lane == 0) { red[w] = s; red[4 + w] = sq; }
    __syncthreads();
    s  = red[0] + red[1] + red[2] + red[3];
    sq = red[4] + red[5] + red[6] + red[7];
    float mean = s / E;
    float var  = (sq - s * mean) / (E - 1);      // ddof=1
    var = fmaxf(var, 0.f);
    float inv = 1.f / (sqrtf(var) + 1e-5f);
    f32x4 g4 = *(const f32x4*)(G + tid * 4);
    f32x4 b4 = *(const f32x4*)(Bt + tid * 4);
    if (O_F32) {
        f32x4 o4;
        for (int j = 0; j < 4; ++j)
            o4[j] = (v[j] - mean) * inv * g4[j] + b4[j];
        *(f32x4*)((float*)Y + base) = o4;
    } else {
        u16x4 o4;
        for (int j = 0; j < 4; ++j)
            o4[j] = f2b((v[j] - mean) * inv * g4[j] + b4[j]);
        *(u16x4*)((unsigned short*)Y + base) = o4;
    }
}

// ---------------------------------------------------------------------------
extern "C" void kernel_launch(void* const* d_in, const int* in_sizes, int n_in,
                              void* d_out, int out_size, void* d_ws, size_t ws_size,
                              hipStream_t stream)
{
    const int B = 4, T = 2048, E = 1024, F = 4096, H = 16;
    const int M = B * T;

    const float* x  = (const float*)d_in[0];
    const int* mask = (const int*)d_in[1];
    const float* Wq = (const float*)d_in[2];
    const float* Wk = (const float*)d_in[3];
    const float* Wv = (const float*)d_in[4];
    const float* Wo = (const float*)d_in[5];
    const float* w1 = (const float*)d_in[6];
    const float* b1 = (const float*)d_in[7];
    const float* w2 = (const float*)d_in[8];
    const float* b2 = (const float*)d_in[9];
    const float* lg = (const float*)d_in[10];
    const float* lb = (const float*)d_in[11];
    float* out = (float*)d_out;

    char* ws = (char*)d_ws;
    const size_t MB = 1024 * 1024;
    unsigned short* xb  = (unsigned short*)(ws);            // 16 MB
    unsigned short* q   = (unsigned short*)(ws + 16 * MB);  // 16 MB
    unsigned short* kk  = (unsigned short*)(ws + 32 * MB);  // 16 MB
    unsigned short* vt  = (unsigned short*)(ws + 48 * MB);  // 16 MB  [B][H][64][T]
    unsigned short* ctx = (unsigned short*)(ws + 64 * MB);  // 16 MB
    unsigned short* hh  = (unsigned short*)(ws + 80 * MB);  // 16 MB (alive after flash)
    unsigned short* mbf = hh;                                // m01 bf16 [B][T], dead before hh
    unsigned short* ff1 = (unsigned short*)(ws);            // 64 MB overlays xb/q/kk/vt (dead)
    unsigned short* ff2 = ctx;                              // ctx dead by then
    unsigned short* att = q;                                // q dead after attention
    unsigned short* Wqb = (unsigned short*)(ws + 96 * MB);  // Wq/Wk/Wv CONTIGUOUS = [3072][1024]
    unsigned short* Wkb = (unsigned short*)(ws + 98 * MB);
    unsigned short* Wvb = (unsigned short*)(ws + 100 * MB);
    unsigned short* Wob = (unsigned short*)(ws + 102 * MB);
    unsigned short* w1b = (unsigned short*)(ws + 104 * MB); // 8 MB
    unsigned short* w2b = (unsigned short*)(ws + 112 * MB); // 8 MB -> 120 MB total

    dim3 blk(256);
    dim3 g512(512);

    // fused casts: x, Wq, Wk, Wv, Wo, w1, w2 (block counts: n_elems/1024)
    CastArgs ca;
    ca.src[0] = x;  ca.dst[0] = xb;
    ca.src[1] = Wq; ca.dst[1] = Wqb;
    ca.src[2] = Wk; ca.dst[2] = Wkb;
    ca.src[3] = Wv; ca.dst[3] = Wvb;
    ca.src[4] = Wo; ca.dst[4] = Wob;
    ca.src[5] = w1; ca.dst[5] = w1b;
    ca.src[6] = w2; ca.dst[6] = w2b;
    int blks[7] = { M * E / 1024, E * E / 1024, E * E / 1024, E * E / 1024,
                    E * E / 1024, F * E / 1024, F * E / 1024 };
    ca.blkcum[0] = 0;
    for (int i = 0; i < 7; ++i) ca.blkcum[i + 1] = ca.blkcum[i] + blks[i];
    cast_all<<<dim3(ca.blkcum[7]), blk, 0, stream>>>(ca);
    mask_bf16<<<dim3(M / 256), blk, 0, stream>>>(mask, mbf, M);

    // fused QKV: N=3072 (Wqb|Wkb|Wvb contiguous); seg 0->q (scaled), 1->kk, 2->vt
    gemm_db<0, 0, 1><<<dim3(3072 / 128, M / 128), blk, 0, stream>>>(
        xb, Wqb, nullptr, mask, q, kk, vt, M, 3072, E);
    flash_attn6<<<dim3((T / 128) * H * B), g512, 0, stream>>>(q, kk, vt, mbf, mask, ctx, T, H, E);
    gemm_db<0, 0, 0><<<dim3(E / 128, M / 128), blk, 0, stream>>>(
        ctx, Wob, nullptr, nullptr, att, nullptr, nullptr, M, E, E);
    ln_residual<1, 0><<<dim3(M), blk, 0, stream>>>(att, x, lg, lb, hh, E);
    gemm_db<1, 1, 0><<<dim3(F / 128, M / 128), blk, 0, stream>>>(
        hh, w1b, b1, nullptr, ff1, nullptr, nullptr, M, F, E);
    gemm_db<1, 0, 0><<<dim3(E / 128, M / 128), blk, 0, stream>>>(
        ff1, w2b, b2, nullptr, ff2, nullptr, nullptr, M, E, F);
    ln_residual<0, 1><<<dim3(M), blk, 0, stream>>>(ff2, hh, lg, lb, out, E);
}